// Round 1
// baseline (1646.247 us; speedup 1.0000x reference)
//
#include <hip/hip_runtime.h>
#include <math.h>

#define N_NODES   20000
#define N_EDGES   320000
#define N_GRAPHS  64
#define IN_FEAT   64
#define HIDDEN    256
#define GRID_F    4
#define NLAYERS   3
#define NEG_SLOPE 0.01f

#define KF 2048   // fourier K = HIDDEN * 8 (cos/sin x k=1..4)
#define KL 320    // line K = IN_FEAT * 5 (degrees 0..4)

// ---------- weight transposes (coalesced-B layout for the GEMMs) ----------
// Bt[l][kk][o], kk = i*8 + t*4 + g  (t=0:cos,1:sin ; g -> k=g+1)
__global__ void transpose_fourier(const float* __restrict__ fc, float* __restrict__ Bt) {
    int idx = blockIdx.x * 256 + threadIdx.x;      // 3*2048*256 total
    int o  = idx & 255;
    int kk = (idx >> 8) & 2047;
    int l  = idx >> 19;                            // 2048*256 = 2^19
    int i = kk >> 3, f = kk & 7, t = f >> 2, g = f & 3;
    Bt[idx] = fc[(((size_t)(l * 2 + t) * HIDDEN + o) * HIDDEN + i) * GRID_F + g];
}

// Wlt[kk][o], kk = i*5 + d
__global__ void transpose_line(const float* __restrict__ wl, float* __restrict__ Wlt) {
    int idx = blockIdx.x * 256 + threadIdx.x;      // 320*256
    int o  = idx & 255;
    int kk = idx >> 8;
    int i = kk / 5, d = kk % 5;
    Wlt[idx] = wl[(o * IN_FEAT + i) * 5 + d];
}

// ---------- CSR build (group edges by dst) ----------
__global__ void count_deg(const int* __restrict__ dst, int* __restrict__ counts) {
    int e = blockIdx.x * 256 + threadIdx.x;
    if (e < N_EDGES) atomicAdd(&counts[dst[e]], 1);
}

__global__ void scan_kernel(const int* __restrict__ counts, int* __restrict__ row_start) {
    __shared__ int buf[1024];
    __shared__ int carry;
    if (threadIdx.x == 0) carry = 0;
    __syncthreads();
    for (int base = 0; base < N_NODES; base += 1024) {
        int i = base + threadIdx.x;
        int v = (i < N_NODES) ? counts[i] : 0;
        buf[threadIdx.x] = v;
        __syncthreads();
        for (int ofs = 1; ofs < 1024; ofs <<= 1) {
            int t = (threadIdx.x >= ofs) ? buf[threadIdx.x - ofs] : 0;
            __syncthreads();
            buf[threadIdx.x] += t;
            __syncthreads();
        }
        if (i < N_NODES) row_start[i] = carry + buf[threadIdx.x] - v;  // exclusive
        __syncthreads();
        if (threadIdx.x == 1023) carry += buf[1023];
        __syncthreads();
    }
    if (threadIdx.x == 0) row_start[N_NODES] = carry;
}

__global__ void fill_csr(const int* __restrict__ src, const int* __restrict__ dst,
                         const int* __restrict__ row_start, int* __restrict__ cursor,
                         int* __restrict__ ssrc) {
    int e = blockIdx.x * 256 + threadIdx.x;
    if (e < N_EDGES) {
        int d = dst[e];
        int pos = row_start[d] + atomicAdd(&cursor[d], 1);
        ssrc[pos] = src[e];
    }
}

// ---------- aggregation: agg[n] = sum_{e: dst[e]==n} h[src[e]] ----------
__global__ void aggregate(const float* __restrict__ h, const int* __restrict__ row_start,
                          const int* __restrict__ ssrc, float* __restrict__ agg) {
    int n = blockIdx.x, t = threadIdx.x;
    int b = row_start[n], e = row_start[n + 1];
    float acc = 0.f;
    for (int j = b; j < e; ++j) {
        int s = ssrc[j];
        acc += h[(size_t)s * HIDDEN + t];
    }
    agg[(size_t)n * HIDDEN + t] = acc;
}

// ---------- kan_line GEMM: out[n][o] = sum_{i,d} x[n][i]^d * W[o][i][d] ----------
// 32-node x 256-out tile per block; thread: og=tid&63 (4 o's), mg=tid>>6 (8 m's)
__global__ __launch_bounds__(256)
void kan_line_gemm(const float* __restrict__ x, const float* __restrict__ Wlt,
                   float* __restrict__ out) {
    __shared__ float At[40 * 32];
    __shared__ float Bs[40 * 256];
    const int tile = blockIdx.x;          // 625 tiles * 32 nodes = 20000
    const int tid  = threadIdx.x;
    const int og = tid & 63, mg = tid >> 6;
    const int mA = tid & 31, ilA = tid >> 5;  // A-fill: 32m x 8i pairs
    float acc[8][4];
    #pragma unroll
    for (int a = 0; a < 8; ++a)
        #pragma unroll
        for (int b = 0; b < 4; ++b) acc[a][b] = 0.f;

    for (int c = 0; c < 8; ++c) {          // 8 chunks of KB=40 (8 i's x 5 degrees)
        int node = tile * 32 + mA;
        float xv = x[(size_t)node * IN_FEAT + c * 8 + ilA];
        float pw = 1.f;
        #pragma unroll
        for (int d = 0; d < 5; ++d) { At[(ilA * 5 + d) * 32 + mA] = pw; pw *= xv; }
        #pragma unroll
        for (int r = 0; r < 40; ++r) Bs[r * 256 + tid] = Wlt[(size_t)(c * 40 + r) * 256 + tid];
        __syncthreads();
        for (int k = 0; k < 40; ++k) {
            float4 a0 = *(const float4*)&At[k * 32 + mg * 8];
            float4 a1 = *(const float4*)&At[k * 32 + mg * 8 + 4];
            float4 bv = *(const float4*)&Bs[k * 256 + og * 4];
            float av[8] = {a0.x, a0.y, a0.z, a0.w, a1.x, a1.y, a1.z, a1.w};
            float bb[4] = {bv.x, bv.y, bv.z, bv.w};
            #pragma unroll
            for (int jm = 0; jm < 8; ++jm)
                #pragma unroll
                for (int j = 0; j < 4; ++j)
                    acc[jm][j] = fmaf(av[jm], bb[j], acc[jm][j]);
        }
        __syncthreads();
    }
    #pragma unroll
    for (int jm = 0; jm < 8; ++jm) {
        int node = tile * 32 + mg * 8 + jm;
        float4 v = make_float4(acc[jm][0], acc[jm][1], acc[jm][2], acc[jm][3]);
        *(float4*)&out[(size_t)node * HIDDEN + og * 4] = v;
    }
}

// ---------- fourier GEMM: hnew = leaky(agg_fourier_features @ Bt + hold) ----------
// In-place safe: writes only its own 32 node rows of hnew(=agg) after all reads.
__global__ __launch_bounds__(256)
void fourier_gemm(const float* __restrict__ agg, const float* __restrict__ hold,
                  const float* __restrict__ Btl, float* __restrict__ hnew) {
    __shared__ float At[64 * 32];
    __shared__ float Bs[64 * 256];
    const int tile = blockIdx.x;
    const int tid  = threadIdx.x;
    const int og = tid & 63, mg = tid >> 6;
    const int mA = tid & 31, ilA = tid >> 5;
    float acc[8][4];
    #pragma unroll
    for (int a = 0; a < 8; ++a)
        #pragma unroll
        for (int b = 0; b < 4; ++b) acc[a][b] = 0.f;

    for (int c = 0; c < 32; ++c) {         // 32 chunks: 8 i's -> 64 features each
        int node = tile * 32 + mA;
        float xv = agg[(size_t)node * HIDDEN + c * 8 + ilA];
        float s1, c1;
        sincosf(xv, &s1, &c1);
        float c2 = c1 * c1 - s1 * s1, s2 = 2.f * s1 * c1;
        float c3 = c2 * c1 - s2 * s1, s3 = s2 * c1 + c2 * s1;
        float c4 = c2 * c2 - s2 * s2, s4 = 2.f * s2 * c2;
        At[(ilA * 8 + 0) * 32 + mA] = c1;
        At[(ilA * 8 + 1) * 32 + mA] = c2;
        At[(ilA * 8 + 2) * 32 + mA] = c3;
        At[(ilA * 8 + 3) * 32 + mA] = c4;
        At[(ilA * 8 + 4) * 32 + mA] = s1;
        At[(ilA * 8 + 5) * 32 + mA] = s2;
        At[(ilA * 8 + 6) * 32 + mA] = s3;
        At[(ilA * 8 + 7) * 32 + mA] = s4;
        #pragma unroll
        for (int r = 0; r < 64; ++r) Bs[r * 256 + tid] = Btl[(size_t)(c * 64 + r) * 256 + tid];
        __syncthreads();
        for (int k = 0; k < 64; ++k) {
            float4 a0 = *(const float4*)&At[k * 32 + mg * 8];
            float4 a1 = *(const float4*)&At[k * 32 + mg * 8 + 4];
            float4 bv = *(const float4*)&Bs[k * 256 + og * 4];
            float av[8] = {a0.x, a0.y, a0.z, a0.w, a1.x, a1.y, a1.z, a1.w};
            float bb[4] = {bv.x, bv.y, bv.z, bv.w};
            #pragma unroll
            for (int jm = 0; jm < 8; ++jm)
                #pragma unroll
                for (int j = 0; j < 4; ++j)
                    acc[jm][j] = fmaf(av[jm], bb[j], acc[jm][j]);
        }
        __syncthreads();
    }
    #pragma unroll
    for (int jm = 0; jm < 8; ++jm) {
        int node = tile * 32 + mg * 8 + jm;
        const float4 r = *(const float4*)&hold[(size_t)node * HIDDEN + og * 4];
        float4 v;
        v.x = acc[jm][0] + r.x;  v.x = v.x > 0.f ? v.x : NEG_SLOPE * v.x;
        v.y = acc[jm][1] + r.y;  v.y = v.y > 0.f ? v.y : NEG_SLOPE * v.y;
        v.z = acc[jm][2] + r.z;  v.z = v.z > 0.f ? v.z : NEG_SLOPE * v.z;
        v.w = acc[jm][3] + r.w;  v.w = v.w > 0.f ? v.w : NEG_SLOPE * v.w;
        *(float4*)&hnew[(size_t)node * HIDDEN + og * 4] = v;
    }
}

// ---------- per-graph average pooling ----------
__global__ void pool_kernel(const float* __restrict__ h, const int* __restrict__ gid,
                            float* __restrict__ pooled, float* __restrict__ gcnt) {
    int n = blockIdx.x, t = threadIdx.x;
    int g = gid[n];
    atomicAdd(&pooled[g * HIDDEN + t], h[(size_t)n * HIDDEN + t]);
    if (t == 0) atomicAdd(&gcnt[g], 1.f);
}

// ---------- readout: sigmoid(sum_i w0[i] + w1[i]*y[g][i] + b) ----------
__global__ void readout(const float* __restrict__ pooled, const float* __restrict__ gcnt,
                        const float* __restrict__ wout, const float* __restrict__ bout,
                        float* __restrict__ out) {
    int g = blockIdx.x, t = threadIdx.x;
    float cnt = fmaxf(gcnt[g], 1.f);
    float y = pooled[g * HIDDEN + t] / cnt;
    float term = wout[t * 2 + 0] + wout[t * 2 + 1] * y;
    #pragma unroll
    for (int o = 32; o > 0; o >>= 1) term += __shfl_down(term, o, 64);
    __shared__ float wsum[4];
    if ((t & 63) == 0) wsum[t >> 6] = term;
    __syncthreads();
    if (t == 0) {
        float s = wsum[0] + wsum[1] + wsum[2] + wsum[3] + bout[0];
        out[g] = 1.f / (1.f + expf(-s));
    }
}

extern "C" void kernel_launch(void* const* d_in, const int* in_sizes, int n_in,
                              void* d_out, int out_size, void* d_ws, size_t ws_size,
                              hipStream_t stream) {
    const float* h_in  = (const float*)d_in[0];
    const int*   src   = (const int*)d_in[1];
    const int*   dst   = (const int*)d_in[2];
    const int*   gid   = (const int*)d_in[3];
    const float* wline = (const float*)d_in[4];
    const float* fcoef = (const float*)d_in[5];
    const float* wout  = (const float*)d_in[6];
    const float* bout  = (const float*)d_in[7];
    float* out = (float*)d_out;

    char* ws = (char*)d_ws;
    size_t off = 0;
    auto alloc = [&](size_t bytes) {
        size_t o = off;
        off += (bytes + 255) & ~size_t(255);
        return o;
    };
    float* buf0      = (float*)(ws + alloc((size_t)N_NODES * HIDDEN * 4));
    float* buf1      = (float*)(ws + alloc((size_t)N_NODES * HIDDEN * 4));
    float* BtF       = (float*)(ws + alloc((size_t)NLAYERS * KF * HIDDEN * 4));
    float* Wlt       = (float*)(ws + alloc((size_t)KL * HIDDEN * 4));
    int*   row_start = (int*)(ws + alloc((size_t)(N_NODES + 1) * 4));
    int*   counts    = (int*)(ws + alloc((size_t)N_NODES * 4));
    int*   cursor    = (int*)(ws + alloc((size_t)N_NODES * 4));
    int*   ssrc      = (int*)(ws + alloc((size_t)N_EDGES * 4));
    float* pooled    = (float*)(ws + alloc((size_t)N_GRAPHS * HIDDEN * 4));
    float* gcnt      = (float*)(ws + alloc((size_t)N_GRAPHS * 4));

    hipMemsetAsync(counts, 0, (size_t)N_NODES * 4, stream);
    hipMemsetAsync(cursor, 0, (size_t)N_NODES * 4, stream);
    hipMemsetAsync(pooled, 0, (size_t)N_GRAPHS * HIDDEN * 4, stream);
    hipMemsetAsync(gcnt, 0, (size_t)N_GRAPHS * 4, stream);

    transpose_fourier<<<6144, 256, 0, stream>>>(fcoef, BtF);
    transpose_line<<<320, 256, 0, stream>>>(wline, Wlt);
    count_deg<<<(N_EDGES + 255) / 256, 256, 0, stream>>>(dst, counts);
    scan_kernel<<<1, 1024, 0, stream>>>(counts, row_start);
    fill_csr<<<(N_EDGES + 255) / 256, 256, 0, stream>>>(src, dst, row_start, cursor, ssrc);

    kan_line_gemm<<<625, 256, 0, stream>>>(h_in, Wlt, buf0);

    float* cur = buf0;
    float* other = buf1;
    for (int l = 0; l < NLAYERS; ++l) {
        aggregate<<<N_NODES, 256, 0, stream>>>(cur, row_start, ssrc, other);
        fourier_gemm<<<625, 256, 0, stream>>>(other, cur, BtF + (size_t)l * KF * HIDDEN, other);
        float* tmp = cur; cur = other; other = tmp;
    }

    pool_kernel<<<N_NODES, 256, 0, stream>>>(cur, gid, pooled, gcnt);
    readout<<<N_GRAPHS, 256, 0, stream>>>(pooled, gcnt, wout, bout, out);
}

// Round 2
// 812.624 us; speedup vs baseline: 2.0258x; 2.0258x over previous
//
#include <hip/hip_runtime.h>
#include <math.h>

#define N_NODES   20000
#define N_PAD     20032   // 313 * 64
#define N_EDGES   320000
#define N_GRAPHS  64
#define IN_FEAT   64
#define HIDDEN    256
#define GRID_F    4
#define NLAYERS   3
#define NEG_SLOPE 0.01f

#define KF 2048   // fourier K = HIDDEN * 8 (cos/sin x k=1..4)
#define KL 320    // line K = IN_FEAT * 5 (degrees 0..4)

typedef _Float16 f16x8 __attribute__((ext_vector_type(8)));
typedef float    f32x4 __attribute__((ext_vector_type(4)));

// ---------- weight transposes ----------
// fp16 Bt[l][o][kk], kk = i*8 + t*4 + g  (t=0:cos,1:sin ; g -> harmonic k=g+1)
// Row-major in kk so a B-fragment (8 consecutive k) is one 16B load.
__global__ void transpose_fourier_f16(const float* __restrict__ fc, _Float16* __restrict__ Bt) {
    int idx = blockIdx.x * 256 + threadIdx.x;      // 3*256*2048 total
    int kk  = idx & 2047;
    int rest = idx >> 11;
    int o = rest & 255;
    int l = rest >> 8;
    int i = kk >> 3, f = kk & 7, t = f >> 2, g = f & 3;
    Bt[idx] = (_Float16)fc[(((size_t)(l * 2 + t) * HIDDEN + o) * HIDDEN + i) * GRID_F + g];
}

// Wlt[kk][o], kk = i*5 + d   (fp32 for the kan_line vector GEMM)
__global__ void transpose_line(const float* __restrict__ wl, float* __restrict__ Wlt) {
    int idx = blockIdx.x * 256 + threadIdx.x;      // 320*256
    int o  = idx & 255;
    int kk = idx >> 8;
    int i = kk / 5, d = kk % 5;
    Wlt[idx] = wl[(o * IN_FEAT + i) * 5 + d];
}

// ---------- CSR build (group edges by dst) ----------
__global__ void count_deg(const int* __restrict__ dst, int* __restrict__ counts) {
    int e = blockIdx.x * 256 + threadIdx.x;
    if (e < N_EDGES) atomicAdd(&counts[dst[e]], 1);
}

__global__ void scan_kernel(const int* __restrict__ counts, int* __restrict__ row_start) {
    __shared__ int buf[1024];
    __shared__ int carry;
    if (threadIdx.x == 0) carry = 0;
    __syncthreads();
    for (int base = 0; base < N_NODES; base += 1024) {
        int i = base + threadIdx.x;
        int v = (i < N_NODES) ? counts[i] : 0;
        buf[threadIdx.x] = v;
        __syncthreads();
        for (int ofs = 1; ofs < 1024; ofs <<= 1) {
            int t = (threadIdx.x >= ofs) ? buf[threadIdx.x - ofs] : 0;
            __syncthreads();
            buf[threadIdx.x] += t;
            __syncthreads();
        }
        if (i < N_NODES) row_start[i] = carry + buf[threadIdx.x] - v;  // exclusive
        __syncthreads();
        if (threadIdx.x == 1023) carry += buf[1023];
        __syncthreads();
    }
    if (threadIdx.x == 0) row_start[N_NODES] = carry;
}

__global__ void fill_csr(const int* __restrict__ src, const int* __restrict__ dst,
                         const int* __restrict__ row_start, int* __restrict__ cursor,
                         int* __restrict__ ssrc) {
    int e = blockIdx.x * 256 + threadIdx.x;
    if (e < N_EDGES) {
        int d = dst[e];
        int pos = row_start[d] + atomicAdd(&cursor[d], 1);
        ssrc[pos] = src[e];
    }
}

// ---------- aggregation: agg[n] = sum_{e: dst[e]==n} h[src[e]] ----------
__global__ void aggregate(const float* __restrict__ h, const int* __restrict__ row_start,
                          const int* __restrict__ ssrc, float* __restrict__ agg) {
    int n = blockIdx.x, t = threadIdx.x;
    int b = row_start[n], e = row_start[n + 1];
    float acc = 0.f;
    for (int j = b; j < e; ++j) {
        int s = ssrc[j];
        acc += h[(size_t)s * HIDDEN + t];
    }
    agg[(size_t)n * HIDDEN + t] = acc;
}

// ---------- kan_line GEMM (fp32 vector ALU; first layer kept high precision) ----------
__global__ __launch_bounds__(256)
void kan_line_gemm(const float* __restrict__ x, const float* __restrict__ Wlt,
                   float* __restrict__ out) {
    __shared__ float At[40 * 32];
    __shared__ float Bs[40 * 256];
    const int tile = blockIdx.x;          // 625 tiles * 32 nodes
    const int tid  = threadIdx.x;
    const int og = tid & 63, mg = tid >> 6;
    const int mA = tid & 31, ilA = tid >> 5;
    float acc[8][4];
    #pragma unroll
    for (int a = 0; a < 8; ++a)
        #pragma unroll
        for (int b = 0; b < 4; ++b) acc[a][b] = 0.f;

    for (int c = 0; c < 8; ++c) {
        int node = tile * 32 + mA;
        float xv = x[(size_t)node * IN_FEAT + c * 8 + ilA];
        float pw = 1.f;
        #pragma unroll
        for (int d = 0; d < 5; ++d) { At[(ilA * 5 + d) * 32 + mA] = pw; pw *= xv; }
        #pragma unroll
        for (int r = 0; r < 40; ++r) Bs[r * 256 + tid] = Wlt[(size_t)(c * 40 + r) * 256 + tid];
        __syncthreads();
        for (int k = 0; k < 40; ++k) {
            float4 a0 = *(const float4*)&At[k * 32 + mg * 8];
            float4 a1 = *(const float4*)&At[k * 32 + mg * 8 + 4];
            float4 bv = *(const float4*)&Bs[k * 256 + og * 4];
            float av[8] = {a0.x, a0.y, a0.z, a0.w, a1.x, a1.y, a1.z, a1.w};
            float bb[4] = {bv.x, bv.y, bv.z, bv.w};
            #pragma unroll
            for (int jm = 0; jm < 8; ++jm)
                #pragma unroll
                for (int j = 0; j < 4; ++j)
                    acc[jm][j] = fmaf(av[jm], bb[j], acc[jm][j]);
        }
        __syncthreads();
    }
    #pragma unroll
    for (int jm = 0; jm < 8; ++jm) {
        int node = tile * 32 + mg * 8 + jm;
        float4 v = make_float4(acc[jm][0], acc[jm][1], acc[jm][2], acc[jm][3]);
        *(float4*)&out[(size_t)node * HIDDEN + og * 4] = v;
    }
}

// ---------- fourier layer via fp16 MFMA ----------
// hnew = leaky(F(agg) @ B + hold), F = [cos(kx),sin(kx)] features, K=2048.
// Block: 256 thr = 4 waves; tile 64 rows x 256 cols (wave w owns cols w*64..w*64+63
// as 4x4 mfma_f32_16x16x32_f16 accumulators). A-fragments computed on the fly:
// per 32-k chunk each thread does one sincos group -> packed 16B frag -> LDS
// (double-buffered 8KB, one barrier/chunk). B fragments are contiguous 16B global
// reads from the fp16 [out][k] transpose, prefetched one chunk ahead.
__global__ __launch_bounds__(256)
void fourier_mfma(const float* __restrict__ agg, const float* __restrict__ hold,
                  const _Float16* __restrict__ Bt, float* __restrict__ hnew) {
    __shared__ _Float16 Alds[2][2048];   // [buf][(mt*64 + lane)*8 + j]
    const int tid  = threadIdx.x;
    const int w    = tid >> 6;
    const int l    = tid & 63;
    const int ln   = l & 15;
    const int quad = l >> 4;
    const int Mbase = blockIdx.x * 64;

    // producer mapping (fixed per thread): one (node, i) per chunk
    const int pnode = Mbase + (tid >> 6) * 16 + (tid & 15);
    const int pioff = (tid >> 4) & 3;

    f32x4 acc[4][4];
    #pragma unroll
    for (int mt = 0; mt < 4; ++mt)
        #pragma unroll
        for (int nt = 0; nt < 4; ++nt)
            acc[mt][nt] = (f32x4){0.f, 0.f, 0.f, 0.f};

    const _Float16* brow[4];
    #pragma unroll
    for (int nt = 0; nt < 4; ++nt)
        brow[nt] = Bt + (size_t)(w * 64 + nt * 16 + ln) * KF + quad * 8;

    // produce chunk kc into buffer b
    #define PRODUCE(kc, b) do {                                                   \
        float xv = agg[(size_t)pnode * HIDDEN + (kc) * 4 + pioff];                \
        float r = xv * 0.15915494309189535f;                                      \
        r -= floorf(r);                                                           \
        float s1 = __builtin_amdgcn_sinf(r);                                      \
        float c1 = __builtin_amdgcn_cosf(r);                                      \
        float c2 = c1 * c1 - s1 * s1, s2 = 2.f * s1 * c1;                         \
        float c3 = c2 * c1 - s2 * s1, s3 = s2 * c1 + c2 * s1;                     \
        float c4 = c2 * c2 - s2 * s2, s4 = 2.f * s2 * c2;                         \
        f16x8 av;                                                                 \
        av[0] = (_Float16)c1; av[1] = (_Float16)c2;                               \
        av[2] = (_Float16)c3; av[3] = (_Float16)c4;                               \
        av[4] = (_Float16)s1; av[5] = (_Float16)s2;                               \
        av[6] = (_Float16)s3; av[7] = (_Float16)s4;                               \
        *(f16x8*)&Alds[b][tid * 8] = av;                                          \
    } while (0)

    f16x8 bfr[2][4];
    #pragma unroll
    for (int nt = 0; nt < 4; ++nt) bfr[0][nt] = *(const f16x8*)(brow[nt]);
    PRODUCE(0, 0);
    __syncthreads();

    #pragma unroll 2
    for (int kc = 0; kc < 64; ++kc) {
        const int cur = kc & 1, nxt = cur ^ 1;
        // A fragments for current chunk (LDS, written last iteration)
        f16x8 afr[4];
        #pragma unroll
        for (int mt = 0; mt < 4; ++mt)
            afr[mt] = *(const f16x8*)&Alds[cur][(mt * 64 + l) * 8];
        // prefetch next chunk's B fragments (global/L2, long latency)
        if (kc < 63) {
            #pragma unroll
            for (int nt = 0; nt < 4; ++nt)
                bfr[nxt][nt] = *(const f16x8*)(brow[nt] + (kc + 1) * 32);
        }
        // 16 MFMAs on current chunk
        #pragma unroll
        for (int mt = 0; mt < 4; ++mt)
            #pragma unroll
            for (int nt = 0; nt < 4; ++nt)
                acc[mt][nt] = __builtin_amdgcn_mfma_f32_16x16x32_f16(
                    afr[mt], bfr[cur][nt], acc[mt][nt], 0, 0, 0);
        // produce next chunk's A into the other buffer
        if (kc < 63) PRODUCE(kc + 1, nxt);
        __syncthreads();
    }
    #undef PRODUCE

    // epilogue: residual + leaky relu, fp32 store
    #pragma unroll
    for (int mt = 0; mt < 4; ++mt) {
        const int row0 = Mbase + mt * 16 + quad * 4;
        #pragma unroll
        for (int r = 0; r < 4; ++r) {
            const int row = row0 + r;
            if (row < N_NODES) {
                #pragma unroll
                for (int nt = 0; nt < 4; ++nt) {
                    const int col = w * 64 + nt * 16 + ln;
                    float v = acc[mt][nt][r] + hold[(size_t)row * HIDDEN + col];
                    v = v > 0.f ? v : NEG_SLOPE * v;
                    hnew[(size_t)row * HIDDEN + col] = v;
                }
            }
        }
    }
}

// ---------- per-graph average pooling ----------
__global__ void pool_kernel(const float* __restrict__ h, const int* __restrict__ gid,
                            float* __restrict__ pooled, float* __restrict__ gcnt) {
    int n = blockIdx.x, t = threadIdx.x;
    int g = gid[n];
    atomicAdd(&pooled[g * HIDDEN + t], h[(size_t)n * HIDDEN + t]);
    if (t == 0) atomicAdd(&gcnt[g], 1.f);
}

// ---------- readout ----------
__global__ void readout(const float* __restrict__ pooled, const float* __restrict__ gcnt,
                        const float* __restrict__ wout, const float* __restrict__ bout,
                        float* __restrict__ out) {
    int g = blockIdx.x, t = threadIdx.x;
    float cnt = fmaxf(gcnt[g], 1.f);
    float y = pooled[g * HIDDEN + t] / cnt;
    float term = wout[t * 2 + 0] + wout[t * 2 + 1] * y;
    #pragma unroll
    for (int o = 32; o > 0; o >>= 1) term += __shfl_down(term, o, 64);
    __shared__ float wsum[4];
    if ((t & 63) == 0) wsum[t >> 6] = term;
    __syncthreads();
    if (t == 0) {
        float s = wsum[0] + wsum[1] + wsum[2] + wsum[3] + bout[0];
        out[g] = 1.f / (1.f + expf(-s));
    }
}

extern "C" void kernel_launch(void* const* d_in, const int* in_sizes, int n_in,
                              void* d_out, int out_size, void* d_ws, size_t ws_size,
                              hipStream_t stream) {
    const float* h_in  = (const float*)d_in[0];
    const int*   src   = (const int*)d_in[1];
    const int*   dst   = (const int*)d_in[2];
    const int*   gid   = (const int*)d_in[3];
    const float* wline = (const float*)d_in[4];
    const float* fcoef = (const float*)d_in[5];
    const float* wout  = (const float*)d_in[6];
    const float* bout  = (const float*)d_in[7];
    float* out = (float*)d_out;

    char* ws = (char*)d_ws;
    size_t off = 0;
    auto alloc = [&](size_t bytes) {
        size_t o = off;
        off += (bytes + 255) & ~size_t(255);
        return o;
    };
    float*     buf0      = (float*)(ws + alloc((size_t)N_PAD * HIDDEN * 4));
    float*     buf1      = (float*)(ws + alloc((size_t)N_PAD * HIDDEN * 4));
    _Float16*  BtF16     = (_Float16*)(ws + alloc((size_t)NLAYERS * KF * HIDDEN * 2));
    float*     Wlt       = (float*)(ws + alloc((size_t)KL * HIDDEN * 4));
    int*       row_start = (int*)(ws + alloc((size_t)(N_NODES + 1) * 4));
    int*       counts    = (int*)(ws + alloc((size_t)N_NODES * 4));
    int*       cursor    = (int*)(ws + alloc((size_t)N_NODES * 4));
    int*       ssrc      = (int*)(ws + alloc((size_t)N_EDGES * 4));
    float*     pooled    = (float*)(ws + alloc((size_t)N_GRAPHS * HIDDEN * 4));
    float*     gcnt      = (float*)(ws + alloc((size_t)N_GRAPHS * 4));

    hipMemsetAsync(counts, 0, (size_t)N_NODES * 4, stream);
    hipMemsetAsync(cursor, 0, (size_t)N_NODES * 4, stream);
    hipMemsetAsync(pooled, 0, (size_t)N_GRAPHS * HIDDEN * 4, stream);
    hipMemsetAsync(gcnt, 0, (size_t)N_GRAPHS * 4, stream);

    transpose_fourier_f16<<<6144, 256, 0, stream>>>(fcoef, BtF16);
    transpose_line<<<320, 256, 0, stream>>>(wline, Wlt);
    count_deg<<<(N_EDGES + 255) / 256, 256, 0, stream>>>(dst, counts);
    scan_kernel<<<1, 1024, 0, stream>>>(counts, row_start);
    fill_csr<<<(N_EDGES + 255) / 256, 256, 0, stream>>>(src, dst, row_start, cursor, ssrc);

    kan_line_gemm<<<625, 256, 0, stream>>>(h_in, Wlt, buf0);

    float* cur = buf0;
    float* other = buf1;
    for (int l = 0; l < NLAYERS; ++l) {
        aggregate<<<N_NODES, 256, 0, stream>>>(cur, row_start, ssrc, other);
        fourier_mfma<<<N_PAD / 64, 256, 0, stream>>>(other, cur,
                                                     BtF16 + (size_t)l * KF * HIDDEN, other);
        float* tmp = cur; cur = other; other = tmp;
    }

    pool_kernel<<<N_NODES, 256, 0, stream>>>(cur, gid, pooled, gcnt);
    readout<<<N_GRAPHS, 256, 0, stream>>>(pooled, gcnt, wout, bout, out);
}

// Round 3
// 657.805 us; speedup vs baseline: 2.5026x; 1.2354x over previous
//
#include <hip/hip_runtime.h>
#include <math.h>

#define N_NODES   20000
#define N_PAD     20032   // 313 * 64
#define N_EDGES   320000
#define N_GRAPHS  64
#define IN_FEAT   64
#define HIDDEN    256
#define GRID_F    4
#define NLAYERS   3
#define NEG_SLOPE 0.01f

#define KF 2048   // fourier K = HIDDEN * 8 (cos/sin x k=1..4)
#define KL 320    // line K = IN_FEAT * 5 (degrees 0..4)
#define NB_SCAN 79  // ceil(20000/256)

typedef _Float16 f16x8 __attribute__((ext_vector_type(8)));
typedef float    f32x4 __attribute__((ext_vector_type(4)));

// ---------- weight transposes ----------
// fp16 Bt[l][o][kk], kk = i*8 + t*4 + g  (t=0:cos,1:sin ; g -> harmonic k=g+1)
__global__ void transpose_fourier_f16(const float* __restrict__ fc, _Float16* __restrict__ Bt) {
    int idx = blockIdx.x * 256 + threadIdx.x;      // 3*256*2048 total
    int kk  = idx & 2047;
    int rest = idx >> 11;
    int o = rest & 255;
    int l = rest >> 8;
    int i = kk >> 3, f = kk & 7, t = f >> 2, g = f & 3;
    Bt[idx] = (_Float16)fc[(((size_t)(l * 2 + t) * HIDDEN + o) * HIDDEN + i) * GRID_F + g];
}

// Wlt[kk][o], kk = i*5 + d   (fp32 for the kan_line vector GEMM)
__global__ void transpose_line(const float* __restrict__ wl, float* __restrict__ Wlt) {
    int idx = blockIdx.x * 256 + threadIdx.x;      // 320*256
    int o  = idx & 255;
    int kk = idx >> 8;
    int i = kk / 5, d = kk % 5;
    Wlt[idx] = wl[(o * IN_FEAT + i) * 5 + d];
}

// ---------- CSR build (group edges by dst) ----------
__global__ void count_deg(const int* __restrict__ dst, int* __restrict__ counts) {
    int e = blockIdx.x * 256 + threadIdx.x;
    if (e < N_EDGES) atomicAdd(&counts[dst[e]], 1);
}

// hierarchical scan: block sums -> scan of sums -> per-block scan + offset
__global__ void block_sums(const int* __restrict__ counts, int* __restrict__ bsum) {
    int i = blockIdx.x * 256 + threadIdx.x;
    int v = (i < N_NODES) ? counts[i] : 0;
    #pragma unroll
    for (int o = 32; o > 0; o >>= 1) v += __shfl_down(v, o, 64);
    __shared__ int ws[4];
    if ((threadIdx.x & 63) == 0) ws[threadIdx.x >> 6] = v;
    __syncthreads();
    if (threadIdx.x == 0) bsum[blockIdx.x] = ws[0] + ws[1] + ws[2] + ws[3];
}

__global__ void scan_mid(const int* __restrict__ bsum, int* __restrict__ bofs,
                         int* __restrict__ row_start) {
    __shared__ int buf[128];
    int t = threadIdx.x;
    int v = (t < NB_SCAN) ? bsum[t] : 0;
    buf[t] = v;
    __syncthreads();
    for (int d = 1; d < 128; d <<= 1) {
        int x = (t >= d) ? buf[t - d] : 0;
        __syncthreads();
        buf[t] += x;
        __syncthreads();
    }
    if (t < NB_SCAN) bofs[t] = buf[t] - v;          // exclusive
    if (t == NB_SCAN - 1) row_start[N_NODES] = buf[t];
}

__global__ void scan_blocks(const int* __restrict__ counts, const int* __restrict__ bofs,
                            int* __restrict__ row_start) {
    int i = blockIdx.x * 256 + threadIdx.x;
    int val = (i < N_NODES) ? counts[i] : 0;
    int lane = threadIdx.x & 63, wid = threadIdx.x >> 6;
    int v = val;
    #pragma unroll
    for (int d = 1; d < 64; d <<= 1) {
        int t = __shfl_up(v, d, 64);
        if (lane >= d) v += t;
    }
    __shared__ int ws[4];
    if (lane == 63) ws[wid] = v;
    __syncthreads();
    int wofs = 0;
    for (int j = 0; j < wid; ++j) wofs += ws[j];
    if (i < N_NODES) row_start[i] = bofs[blockIdx.x] + wofs + v - val;  // exclusive
}

__global__ void fill_csr(const int* __restrict__ src, const int* __restrict__ dst,
                         const int* __restrict__ row_start, int* __restrict__ cursor,
                         int* __restrict__ ssrc) {
    int e = blockIdx.x * 256 + threadIdx.x;
    if (e < N_EDGES) {
        int d = dst[e];
        int pos = row_start[d] + atomicAdd(&cursor[d], 1);
        ssrc[pos] = src[e];
    }
}

// ---------- aggregation: agg[n] = sum_{e: dst[e]==n} h[src[e]] ----------
__global__ void aggregate(const float* __restrict__ h, const int* __restrict__ row_start,
                          const int* __restrict__ ssrc, float* __restrict__ agg) {
    int n = blockIdx.x, t = threadIdx.x;
    int b = row_start[n], e = row_start[n + 1];
    float acc = 0.f;
    for (int j = b; j < e; ++j) {
        int s = ssrc[j];
        acc += h[(size_t)s * HIDDEN + t];
    }
    agg[(size_t)n * HIDDEN + t] = acc;
}

// ---------- kan_line GEMM (fp32 vector ALU; first layer kept high precision) ----------
__global__ __launch_bounds__(256)
void kan_line_gemm(const float* __restrict__ x, const float* __restrict__ Wlt,
                   float* __restrict__ out) {
    __shared__ float At[40 * 32];
    __shared__ float Bs[40 * 256];
    const int tile = blockIdx.x;          // 625 tiles * 32 nodes
    const int tid  = threadIdx.x;
    const int og = tid & 63, mg = tid >> 6;
    const int mA = tid & 31, ilA = tid >> 5;
    float acc[8][4];
    #pragma unroll
    for (int a = 0; a < 8; ++a)
        #pragma unroll
        for (int b = 0; b < 4; ++b) acc[a][b] = 0.f;

    for (int c = 0; c < 8; ++c) {
        int node = tile * 32 + mA;
        float xv = x[(size_t)node * IN_FEAT + c * 8 + ilA];
        float pw = 1.f;
        #pragma unroll
        for (int d = 0; d < 5; ++d) { At[(ilA * 5 + d) * 32 + mA] = pw; pw *= xv; }
        #pragma unroll
        for (int r = 0; r < 40; ++r) Bs[r * 256 + tid] = Wlt[(size_t)(c * 40 + r) * 256 + tid];
        __syncthreads();
        for (int k = 0; k < 40; ++k) {
            float4 a0 = *(const float4*)&At[k * 32 + mg * 8];
            float4 a1 = *(const float4*)&At[k * 32 + mg * 8 + 4];
            float4 bv = *(const float4*)&Bs[k * 256 + og * 4];
            float av[8] = {a0.x, a0.y, a0.z, a0.w, a1.x, a1.y, a1.z, a1.w};
            float bb[4] = {bv.x, bv.y, bv.z, bv.w};
            #pragma unroll
            for (int jm = 0; jm < 8; ++jm)
                #pragma unroll
                for (int j = 0; j < 4; ++j)
                    acc[jm][j] = fmaf(av[jm], bb[j], acc[jm][j]);
        }
        __syncthreads();
    }
    #pragma unroll
    for (int jm = 0; jm < 8; ++jm) {
        int node = tile * 32 + mg * 8 + jm;
        float4 v = make_float4(acc[jm][0], acc[jm][1], acc[jm][2], acc[jm][3]);
        *(float4*)&out[(size_t)node * HIDDEN + og * 4] = v;
    }
}

// ---------- fourier layer via fp16 MFMA ----------
__global__ __launch_bounds__(256)
void fourier_mfma(const float* __restrict__ agg, const float* __restrict__ hold,
                  const _Float16* __restrict__ Bt, float* __restrict__ hnew) {
    __shared__ _Float16 Alds[2][2048];   // [buf][(mt*64 + lane)*8 + j]
    const int tid  = threadIdx.x;
    const int w    = tid >> 6;
    const int l    = tid & 63;
    const int ln   = l & 15;
    const int quad = l >> 4;
    const int Mbase = blockIdx.x * 64;

    const int pnode = Mbase + (tid >> 6) * 16 + (tid & 15);
    const int pioff = (tid >> 4) & 3;

    f32x4 acc[4][4];
    #pragma unroll
    for (int mt = 0; mt < 4; ++mt)
        #pragma unroll
        for (int nt = 0; nt < 4; ++nt)
            acc[mt][nt] = (f32x4){0.f, 0.f, 0.f, 0.f};

    const _Float16* brow[4];
    #pragma unroll
    for (int nt = 0; nt < 4; ++nt)
        brow[nt] = Bt + (size_t)(w * 64 + nt * 16 + ln) * KF + quad * 8;

    #define PRODUCE(kc, b) do {                                                   \
        float xv = agg[(size_t)pnode * HIDDEN + (kc) * 4 + pioff];                \
        float r = xv * 0.15915494309189535f;                                      \
        r -= floorf(r);                                                           \
        float s1 = __builtin_amdgcn_sinf(r);                                      \
        float c1 = __builtin_amdgcn_cosf(r);                                      \
        float c2 = c1 * c1 - s1 * s1, s2 = 2.f * s1 * c1;                         \
        float c3 = c2 * c1 - s2 * s1, s3 = s2 * c1 + c2 * s1;                     \
        float c4 = c2 * c2 - s2 * s2, s4 = 2.f * s2 * c2;                         \
        f16x8 av;                                                                 \
        av[0] = (_Float16)c1; av[1] = (_Float16)c2;                               \
        av[2] = (_Float16)c3; av[3] = (_Float16)c4;                               \
        av[4] = (_Float16)s1; av[5] = (_Float16)s2;                               \
        av[6] = (_Float16)s3; av[7] = (_Float16)s4;                               \
        *(f16x8*)&Alds[b][tid * 8] = av;                                          \
    } while (0)

    f16x8 bfr[2][4];
    #pragma unroll
    for (int nt = 0; nt < 4; ++nt) bfr[0][nt] = *(const f16x8*)(brow[nt]);
    PRODUCE(0, 0);
    __syncthreads();

    #pragma unroll 2
    for (int kc = 0; kc < 64; ++kc) {
        const int cur = kc & 1, nxt = cur ^ 1;
        f16x8 afr[4];
        #pragma unroll
        for (int mt = 0; mt < 4; ++mt)
            afr[mt] = *(const f16x8*)&Alds[cur][(mt * 64 + l) * 8];
        if (kc < 63) {
            #pragma unroll
            for (int nt = 0; nt < 4; ++nt)
                bfr[nxt][nt] = *(const f16x8*)(brow[nt] + (kc + 1) * 32);
        }
        #pragma unroll
        for (int mt = 0; mt < 4; ++mt)
            #pragma unroll
            for (int nt = 0; nt < 4; ++nt)
                acc[mt][nt] = __builtin_amdgcn_mfma_f32_16x16x32_f16(
                    afr[mt], bfr[cur][nt], acc[mt][nt], 0, 0, 0);
        if (kc < 63) PRODUCE(kc + 1, nxt);
        __syncthreads();
    }
    #undef PRODUCE

    #pragma unroll
    for (int mt = 0; mt < 4; ++mt) {
        const int row0 = Mbase + mt * 16 + quad * 4;
        #pragma unroll
        for (int r = 0; r < 4; ++r) {
            const int row = row0 + r;
            if (row < N_NODES) {
                #pragma unroll
                for (int nt = 0; nt < 4; ++nt) {
                    const int col = w * 64 + nt * 16 + ln;
                    float v = acc[mt][nt][r] + hold[(size_t)row * HIDDEN + col];
                    v = v > 0.f ? v : NEG_SLOPE * v;
                    hnew[(size_t)row * HIDDEN + col] = v;
                }
            }
        }
    }
}

// ---------- per-graph pooling: gid is SORTED -> segmented register accumulation ----
__global__ void graph_bounds(const int* __restrict__ gid, int* __restrict__ gstart) {
    int g = threadIdx.x;
    if (g < N_GRAPHS) {
        int lo = 0, hi = N_NODES;
        while (lo < hi) { int mid = (lo + hi) >> 1; if (gid[mid] < g) lo = mid + 1; else hi = mid; }
        gstart[g] = lo;
    } else if (g == N_GRAPHS) {
        gstart[g] = N_NODES;
    }
}

__global__ __launch_bounds__(256)
void pool_seg(const float* __restrict__ h, const int* __restrict__ gid,
              float* __restrict__ pooled) {
    const int c = threadIdx.x;
    const int s = blockIdx.x * 128;
    const int e = min(s + 128, N_NODES);
    float acc = 0.f;
    int g = gid[s];
    for (int n = s; n < e; ++n) {
        int gn = gid[n];
        if (gn != g) {
            atomicAdd(&pooled[g * HIDDEN + c], acc);
            acc = 0.f;
            g = gn;
        }
        acc += h[(size_t)n * HIDDEN + c];
    }
    atomicAdd(&pooled[g * HIDDEN + c], acc);
}

// ---------- readout ----------
__global__ void readout(const float* __restrict__ pooled, const int* __restrict__ gstart,
                        const float* __restrict__ wout, const float* __restrict__ bout,
                        float* __restrict__ out) {
    int g = blockIdx.x, t = threadIdx.x;
    float cnt = fmaxf((float)(gstart[g + 1] - gstart[g]), 1.f);
    float y = pooled[g * HIDDEN + t] / cnt;
    float term = wout[t * 2 + 0] + wout[t * 2 + 1] * y;
    #pragma unroll
    for (int o = 32; o > 0; o >>= 1) term += __shfl_down(term, o, 64);
    __shared__ float wsum[4];
    if ((t & 63) == 0) wsum[t >> 6] = term;
    __syncthreads();
    if (t == 0) {
        float s = wsum[0] + wsum[1] + wsum[2] + wsum[3] + bout[0];
        out[g] = 1.f / (1.f + expf(-s));
    }
}

extern "C" void kernel_launch(void* const* d_in, const int* in_sizes, int n_in,
                              void* d_out, int out_size, void* d_ws, size_t ws_size,
                              hipStream_t stream) {
    const float* h_in  = (const float*)d_in[0];
    const int*   src   = (const int*)d_in[1];
    const int*   dst   = (const int*)d_in[2];
    const int*   gid   = (const int*)d_in[3];
    const float* wline = (const float*)d_in[4];
    const float* fcoef = (const float*)d_in[5];
    const float* wout  = (const float*)d_in[6];
    const float* bout  = (const float*)d_in[7];
    float* out = (float*)d_out;

    char* ws = (char*)d_ws;
    size_t off = 0;
    auto alloc = [&](size_t bytes) {
        size_t o = off;
        off += (bytes + 255) & ~size_t(255);
        return o;
    };
    float*     buf0      = (float*)(ws + alloc((size_t)N_PAD * HIDDEN * 4));
    float*     buf1      = (float*)(ws + alloc((size_t)N_PAD * HIDDEN * 4));
    _Float16*  BtF16     = (_Float16*)(ws + alloc((size_t)NLAYERS * KF * HIDDEN * 2));
    float*     Wlt       = (float*)(ws + alloc((size_t)KL * HIDDEN * 4));
    int*       row_start = (int*)(ws + alloc((size_t)(N_NODES + 1) * 4));
    int*       counts    = (int*)(ws + alloc((size_t)N_NODES * 4));
    int*       cursor    = (int*)(ws + alloc((size_t)N_NODES * 4));
    int*       ssrc      = (int*)(ws + alloc((size_t)N_EDGES * 4));
    int*       bsum      = (int*)(ws + alloc((size_t)128 * 4));
    int*       bofs      = (int*)(ws + alloc((size_t)128 * 4));
    int*       gstart    = (int*)(ws + alloc((size_t)(N_GRAPHS + 1) * 4));
    float*     pooled    = (float*)(ws + alloc((size_t)N_GRAPHS * HIDDEN * 4));

    hipMemsetAsync(counts, 0, (size_t)N_NODES * 4, stream);
    hipMemsetAsync(cursor, 0, (size_t)N_NODES * 4, stream);
    hipMemsetAsync(pooled, 0, (size_t)N_GRAPHS * HIDDEN * 4, stream);

    transpose_fourier_f16<<<6144, 256, 0, stream>>>(fcoef, BtF16);
    transpose_line<<<320, 256, 0, stream>>>(wline, Wlt);
    count_deg<<<(N_EDGES + 255) / 256, 256, 0, stream>>>(dst, counts);
    block_sums<<<NB_SCAN, 256, 0, stream>>>(counts, bsum);
    scan_mid<<<1, 128, 0, stream>>>(bsum, bofs, row_start);
    scan_blocks<<<NB_SCAN, 256, 0, stream>>>(counts, bofs, row_start);
    fill_csr<<<(N_EDGES + 255) / 256, 256, 0, stream>>>(src, dst, row_start, cursor, ssrc);
    graph_bounds<<<1, 128, 0, stream>>>(gid, gstart);

    kan_line_gemm<<<625, 256, 0, stream>>>(h_in, Wlt, buf0);

    float* cur = buf0;
    float* other = buf1;
    for (int l = 0; l < NLAYERS; ++l) {
        aggregate<<<N_NODES, 256, 0, stream>>>(cur, row_start, ssrc, other);
        fourier_mfma<<<N_PAD / 64, 256, 0, stream>>>(other, cur,
                                                     BtF16 + (size_t)l * KF * HIDDEN, other);
        float* tmp = cur; cur = other; other = tmp;
    }

    pool_seg<<<(N_NODES + 127) / 128, 256, 0, stream>>>(cur, gid, pooled);
    readout<<<N_GRAPHS, 256, 0, stream>>>(pooled, gstart, wout, bout, out);
}